// Round 3
// baseline (469.364 us; speedup 1.0000x reference)
//
#include <hip/hip_runtime.h>
#include <math.h>

// Problem constants
#define BB 128
#define SS 512
#define HH 768
#define PPOS 512       // P
#define NEGC (-1.0e9f)
#define NINF (-1.0e12f)

// Workspace layout (float offsets). Regions time-multiplexed:
// phase 1 (kvec/weff/fused pool): KVEC/WEFF/C + PP/PS/PO/PZ partials
// phase 2 (reduce onward): CAT overlays dead KVEC..WEFF, CTXA..F1 overlay PP.
#define OFF_KVEC   0          // 2624  (41*64)
#define OFF_WEFF   2624       // 768
#define OFF_C      3392       // 1
#define OFF_CAT    0          // 294912 (B*2304) [subj|obj|ctx], written by k_reduce/k_ln
#define OFF_POOLED 294912     // 98304 (B*H)
#define OFF_PP     393216     // 786432 (B*8*H) partial exp-weighted pool
#define OFF_PS     1179648    // 786432 partial subj max
#define OFF_PO     1966080    // 786432 partial obj max
#define OFF_PZ     2752512    // 1024 (B*8) partial softmax denominators (end ~11MB)
#define OFF_CTXA   393216     // 98304 (overlays PP after k_reduce)
#define OFF_CTXB   491520     // 98304
#define OFF_F1     589824     // 98304

__device__ __forceinline__ float gelu_f(float x) {
    return 0.5f * x * (1.0f + erff(x * 0.70710678118654752f));
}
__device__ __forceinline__ float dot4(float4 a, float4 b) {
    return a.x*b.x + a.y*b.y + a.z*b.z + a.w*b.w;
}

// ---------------------------------------------------------------------------
// LDS-shared-W block GEMM: C[M,N] = act(A[M,K] @ W[N,K]^T + bias)
// Block = 4 waves = 8m x 16n tile. All 4 waves consume the SAME 16 W rows,
// staged through LDS in chunks of 64 float4s (256 floats) per row, so W is
// read from L2 once per 8 m-rows instead of once per 2 (4x less L2 traffic
// than the old wave-tile k_mm) while keeping the same wave count (12/CU).
// LDS rows padded to 65 float4s: unpadded, the 16 n-lanes of a ds_read_b128
// hit the same bank (stride 1024B) = 16-way conflict; +1 float4 spreads them.
// Requires K4 % 64 == 0, N % 16 == 0, M % 8 == 0.
// ---------------------------------------------------------------------------
template<int K4, int ACT>
__global__ __launch_bounds__(256) void k_mmL(const float* __restrict__ A,
        const float* __restrict__ W, const float* __restrict__ bias,
        float* __restrict__ C, int M, int N) {
    __shared__ float4 lw[16 * 65];
    int t = threadIdx.x, lane = t & 63, wave = t >> 6;
    int ntn = N >> 4;
    int bm = blockIdx.x / ntn;
    int bn = blockIdx.x - bm * ntn;
    int m0 = bm * 8 + wave * 2;
    int n_sub = lane >> 2, ks = lane & 3;
    int n0 = (bn << 4) + n_sub;
    const float4* A4 = (const float4*)A + (size_t)m0 * K4;
    const float4* Wb = (const float4*)W;
    float acc0 = 0.f, acc1 = 0.f;
    for (int c0 = 0; c0 < K4; c0 += 64) {
        __syncthreads();   // protect lw from previous chunk's readers
        #pragma unroll
        for (int i = 0; i < 4; ++i) {
            int li = t * 4 + i;              // 0..1023, stays within one row
            int r = li >> 6, j = li & 63;
            lw[r * 65 + j] = Wb[(size_t)((bn << 4) + r) * K4 + c0 + j];
        }
        __syncthreads();
        const float4* lrow = lw + n_sub * 65;
        #pragma unroll 4
        for (int j = ks; j < 64; j += 4) {
            float4 wv = lrow[j];
            acc0 += dot4(A4[c0 + j], wv);
            acc1 += dot4(A4[K4 + c0 + j], wv);
        }
    }
    acc0 += __shfl_xor(acc0, 1, 64); acc0 += __shfl_xor(acc0, 2, 64);
    acc1 += __shfl_xor(acc1, 1, 64); acc1 += __shfl_xor(acc1, 2, 64);
    if (ks == 0) {
        float b = bias ? bias[n0] : 0.f;
        float v0 = acc0 + b, v1 = acc1 + b;
        if (ACT == 1) { v0 = gelu_f(v0); v1 = gelu_f(v1); }
        C[(size_t)m0 * N + n0] = v0;
        C[(size_t)(m0 + 1) * N + n0] = v1;
    }
}

// K1a: kvec[l,k] = sum_d label_emb[l+1,d]*WK[l,k,d] + bK[l,k].  One wave/output.
// Blocks 0..3 additionally zero-init WEFF (768) and C for k_weff2's atomics.
__global__ __launch_bounds__(256) void k_kvec2(const float* __restrict__ label_emb,
        const float* __restrict__ WK, const float* __restrict__ bK,
        float* __restrict__ ws) {
    if (blockIdx.x < 3) ws[OFF_WEFF + blockIdx.x * 256 + threadIdx.x] = 0.f;
    if (blockIdx.x == 3 && threadIdx.x == 0) ws[OFF_C] = 0.f;
    int lane = threadIdx.x & 63;
    int idx = (blockIdx.x * 256 + threadIdx.x) >> 6;   // 0..2623
    int l = idx >> 6;
    const float4* lab4 = (const float4*)(label_emb + (size_t)(l + 1) * 300);
    const float4* wk4  = (const float4*)(WK + (size_t)idx * 300);
    float acc = dot4(lab4[lane], wk4[lane]);           // 75 float4s per row
    if (lane < 11) acc += dot4(lab4[64 + lane], wk4[64 + lane]);
    #pragma unroll
    for (int off = 32; off > 0; off >>= 1) acc += __shfl_xor(acc, off, 64);
    if (lane == 0) ws[OFF_KVEC + idx] = acc + bK[idx];
}

// K1b: w_eff[h] += sum over j-chunk kvec[j]*WQ[j,h] (atomics), + c = kvec.bQ
__global__ __launch_bounds__(256) void k_weff2(const float* __restrict__ WQ,
        const float* __restrict__ bQ, float* __restrict__ ws) {
    int lane = threadIdx.x & 63;
    int w = (blockIdx.x * 256 + threadIdx.x) >> 6;
    if (w < 492) {
        int jc = w / 12, hg = w % 12;
        int h = hg * 64 + lane;
        const float* wq = WQ + (size_t)(jc * 64) * HH + h;
        const float* kv = ws + OFF_KVEC + jc * 64;
        float acc = 0.f;
        #pragma unroll 8
        for (int j = 0; j < 64; ++j) acc += kv[j] * wq[(size_t)j * HH];
        atomicAdd(&ws[OFF_WEFF + h], acc);
    } else if (w == 492) {
        float acc = 0.f;
        for (int j = lane; j < 2624; j += 64) acc += ws[OFF_KVEC + j] * bQ[j];
        #pragma unroll
        for (int off = 32; off > 0; off >>= 1) acc += __shfl_xor(acc, off, 64);
        if (lane == 0) atomicAdd(&ws[OFF_C], acc);
    }
}

// K2+K4 fused: single pass over inputs. Per row: score = (x.w_eff + c)/8,
// e = masked ? 0 : exp(score) (scores are O(0.4) by construction -> safe
// without max-subtraction; masked rows underflow to exactly 0 in the
// reference too). Accumulate sum(e*x), sum(e), and subj/obj masked maxes.
__global__ __launch_bounds__(256) void k_fused(const float* __restrict__ inputs,
        const int* __restrict__ pos_ids, const int* __restrict__ subj_pos,
        const int* __restrict__ obj_pos, float* __restrict__ ws) {
    __shared__ float l_pe[4][768];
    __shared__ float l_sm[4][768];
    __shared__ float l_om[4][768];
    __shared__ float l_z[4];
    __shared__ int l_mask[64];
    int chunk = blockIdx.x, b = blockIdx.y;
    int t = threadIdx.x, wave = t >> 6, lane = t & 63;
    int row0 = b * SS + chunk * 64;           // first global row of this block
    if (t < 64) {
        int g = row0 + t;
        int sp = subj_pos[g], op = obj_pos[g], pi = pos_ids[g];
        int m = ((sp == PPOS) | (op == PPOS) | (pi == 0)) ? 1 : 0;
        if (sp == PPOS) m |= 2;
        if (op == PPOS) m |= 4;
        l_mask[t] = m;
    }
    const float4* w4 = (const float4*)(ws + OFF_WEFF);
    float c = ws[OFF_C];
    float4 w0 = w4[lane], w1 = w4[64 + lane], w2 = w4[128 + lane];
    __syncthreads();
    const float4* in4 = (const float4*)inputs;
    float4 pe0 = make_float4(0.f, 0.f, 0.f, 0.f);
    float4 pe1 = pe0, pe2 = pe0;
    float4 sm0 = make_float4(NINF, NINF, NINF, NINF);
    float4 sm1 = sm0, sm2 = sm0, om0 = sm0, om1 = sm0, om2 = sm0;
    float z = 0.f;
    int rbase = wave * 16;                    // rows within chunk for this wave
    #pragma unroll 4
    for (int r = 0; r < 16; ++r) {
        int s = rbase + r;
        const float4* x4 = in4 + (size_t)(row0 + s) * 192;
        float4 x0 = x4[lane], x1 = x4[64 + lane], x2 = x4[128 + lane];
        float acc = dot4(x0, w0) + dot4(x1, w1) + dot4(x2, w2);
        #pragma unroll
        for (int off = 32; off > 0; off >>= 1) acc += __shfl_xor(acc, off, 64);
        int mk = l_mask[s];
        float e = (mk & 1) ? 0.f : __expf((acc + c) * 0.125f);
        z += e;
        pe0.x += e * x0.x; pe0.y += e * x0.y; pe0.z += e * x0.z; pe0.w += e * x0.w;
        pe1.x += e * x1.x; pe1.y += e * x1.y; pe1.z += e * x1.z; pe1.w += e * x1.w;
        pe2.x += e * x2.x; pe2.y += e * x2.y; pe2.z += e * x2.z; pe2.w += e * x2.w;
        if (mk & 2) {
            sm0.x = fmaxf(sm0.x, x0.x); sm0.y = fmaxf(sm0.y, x0.y);
            sm0.z = fmaxf(sm0.z, x0.z); sm0.w = fmaxf(sm0.w, x0.w);
            sm1.x = fmaxf(sm1.x, x1.x); sm1.y = fmaxf(sm1.y, x1.y);
            sm1.z = fmaxf(sm1.z, x1.z); sm1.w = fmaxf(sm1.w, x1.w);
            sm2.x = fmaxf(sm2.x, x2.x); sm2.y = fmaxf(sm2.y, x2.y);
            sm2.z = fmaxf(sm2.z, x2.z); sm2.w = fmaxf(sm2.w, x2.w);
        }
        if (mk & 4) {
            om0.x = fmaxf(om0.x, x0.x); om0.y = fmaxf(om0.y, x0.y);
            om0.z = fmaxf(om0.z, x0.z); om0.w = fmaxf(om0.w, x0.w);
            om1.x = fmaxf(om1.x, x1.x); om1.y = fmaxf(om1.y, x1.y);
            om1.z = fmaxf(om1.z, x1.z); om1.w = fmaxf(om1.w, x1.w);
            om2.x = fmaxf(om2.x, x2.x); om2.y = fmaxf(om2.y, x2.y);
            om2.z = fmaxf(om2.z, x2.z); om2.w = fmaxf(om2.w, x2.w);
        }
    }
    // wave partials -> LDS (h layout: [lane*4..+3], [256+..], [512+..])
    ((float4*)l_pe[wave])[lane] = pe0;
    ((float4*)l_pe[wave])[64 + lane] = pe1;
    ((float4*)l_pe[wave])[128 + lane] = pe2;
    ((float4*)l_sm[wave])[lane] = sm0;
    ((float4*)l_sm[wave])[64 + lane] = sm1;
    ((float4*)l_sm[wave])[128 + lane] = sm2;
    ((float4*)l_om[wave])[lane] = om0;
    ((float4*)l_om[wave])[64 + lane] = om1;
    ((float4*)l_om[wave])[128 + lane] = om2;
    if (lane == 0) l_z[wave] = z;
    __syncthreads();
    if (t < 192) {
        float4 p = make_float4(0.f, 0.f, 0.f, 0.f);
        float4 s = make_float4(NINF, NINF, NINF, NINF);
        float4 o = s;
        #pragma unroll
        for (int w = 0; w < 4; ++w) {
            float4 vp = ((float4*)l_pe[w])[t];
            float4 vs = ((float4*)l_sm[w])[t];
            float4 vo = ((float4*)l_om[w])[t];
            p.x += vp.x; p.y += vp.y; p.z += vp.z; p.w += vp.w;
            s.x = fmaxf(s.x, vs.x); s.y = fmaxf(s.y, vs.y);
            s.z = fmaxf(s.z, vs.z); s.w = fmaxf(s.w, vs.w);
            o.x = fmaxf(o.x, vo.x); o.y = fmaxf(o.y, vo.y);
            o.z = fmaxf(o.z, vo.z); o.w = fmaxf(o.w, vo.w);
        }
        size_t oo = (size_t)(b * 8 + chunk) * 192 + t;
        ((float4*)(ws + OFF_PP))[oo] = p;
        ((float4*)(ws + OFF_PS))[oo] = s;
        ((float4*)(ws + OFF_PO))[oo] = o;
    }
    if (t == 0) ws[OFF_PZ + b * 8 + chunk] = l_z[0] + l_z[1] + l_z[2] + l_z[3];
}

// K5: reduce 8 chunk partials -> pooled (/Z), and subj/obj maxes into CAT
__global__ void k_reduce(float* __restrict__ ws) {
    int i = blockIdx.x * 256 + threadIdx.x;   // 0..98303
    int b = i / HH, h = i - b * HH;
    float p = 0.f, sm = NINF, om = NINF, zt = 0.f;
    #pragma unroll
    for (int j = 0; j < 8; ++j) {
        int o = (b * 8 + j) * HH + h;
        p += ws[OFF_PP + o];
        sm = fmaxf(sm, ws[OFF_PS + o]);
        om = fmaxf(om, ws[OFF_PO + o]);
        zt += ws[OFF_PZ + b * 8 + j];
    }
    ws[OFF_POOLED + i] = p / zt;
    ws[OFF_CAT + (size_t)b * 2304 + h] = sm;
    ws[OFF_CAT + (size_t)b * 2304 + 768 + h] = om;
}

// K8: layernorm -> ctx output (d_out offset 5376) AND cat[:, 1536:2304]
__global__ void k_ln(const float* __restrict__ ln_g, const float* __restrict__ ln_b,
                     float* __restrict__ ws, float* __restrict__ out) {
    __shared__ float red[256];
    __shared__ float red2[256];
    int b = blockIdx.x, t = threadIdx.x;
    const float* x = ws + OFF_CTXB + (size_t)b * HH;
    float a0 = x[t], a1 = x[t + 256], a2 = x[t + 512];
    red[t]  = a0 + a1 + a2;
    red2[t] = a0 * a0 + a1 * a1 + a2 * a2;
    __syncthreads();
    for (int s2 = 128; s2 > 0; s2 >>= 1) {
        if (t < s2) { red[t] += red[t + s2]; red2[t] += red2[t + s2]; }
        __syncthreads();
    }
    float mu  = red[0] * (1.0f / 768.0f);
    float var = red2[0] * (1.0f / 768.0f) - mu * mu;
    float inv = rsqrtf(var + 1e-5f);
    float* o = out + 5376 + (size_t)b * HH;
    float* cc = ws + OFF_CAT + (size_t)b * 2304 + 1536;
    float r0 = (a0 - mu) * inv * ln_g[t]       + ln_b[t];
    float r1 = (a1 - mu) * inv * ln_g[t + 256] + ln_b[t + 256];
    float r2 = (a2 - mu) * inv * ln_g[t + 512] + ln_b[t + 512];
    o[t] = r0; o[t + 256] = r1; o[t + 512] = r2;
    cc[t] = r0; cc[t + 256] = r1; cc[t + 512] = r2;
}

// Tail fusion: feats2 = gelu(F1 @ out_w.T + out_b) then logits = feats2 @ le.T
// Both are row-local per batch -> one block per b, feats2 row held in LDS.
__global__ __launch_bounds__(256) void k_tail(const float* __restrict__ F1,
        const float* __restrict__ out_w, const float* __restrict__ out_b,
        const float* __restrict__ label_emb, float* __restrict__ out) {
    __shared__ float f2s[304];
    int b = blockIdx.x, t = threadIdx.x, lane = t & 63, wave = t >> 6;
    const float4* A4 = (const float4*)(F1 + (size_t)b * HH);
    int n_sub = lane >> 2, ks = lane & 3;
    // phase 1: 19 n-tiles of 16 across 4 waves (K = 768 = 192 float4s)
    for (int nt = wave; nt < 19; nt += 4) {
        int n0 = nt * 16 + n_sub;
        int nr = (n0 < 300) ? n0 : 299;
        const float4* w_row = (const float4*)out_w + (size_t)nr * 192;
        float acc = 0.f;
        #pragma unroll 4
        for (int j = ks; j < 192; j += 4) acc += dot4(A4[j], w_row[j]);
        acc += __shfl_xor(acc, 1, 64);
        acc += __shfl_xor(acc, 2, 64);
        if (ks == 0 && n0 < 300) f2s[n0] = gelu_f(acc + out_b[n0]);
    }
    __syncthreads();
    // phase 2: logits row (42 outputs, K = 300); 4 lanes per output
    if (t < 168) {
        int n = t >> 2, k4 = t & 3;
        const float* le = label_emb + (size_t)n * 300;
        float acc = 0.f;
        for (int k = k4; k < 300; k += 4) acc += f2s[k] * le[k];
        acc += __shfl_xor(acc, 1, 64);
        acc += __shfl_xor(acc, 2, 64);
        if (k4 == 0) out[(size_t)b * 42 + n] = acc;
    }
}

extern "C" void kernel_launch(void* const* d_in, const int* in_sizes, int n_in,
                              void* d_out, int out_size, void* d_ws, size_t ws_size,
                              hipStream_t stream) {
    const float* inputs    = (const float*)d_in[0];
    const int*   pos_ids   = (const int*)d_in[1];
    const int*   subj_pos  = (const int*)d_in[3];
    const int*   obj_pos   = (const int*)d_in[4];
    const float* WQ        = (const float*)d_in[6];
    const float* bQ        = (const float*)d_in[7];
    const float* WK        = (const float*)d_in[8];
    const float* bK        = (const float*)d_in[9];
    const float* WV_w      = (const float*)d_in[10];
    const float* WV_b      = (const float*)d_in[11];
    const float* Wout_w    = (const float*)d_in[12];
    const float* Wout_b    = (const float*)d_in[13];
    const float* ln_g      = (const float*)d_in[14];
    const float* ln_b      = (const float*)d_in[15];
    const float* label_emb = (const float*)d_in[16];
    const float* feat_w    = (const float*)d_in[17];
    const float* feat_b    = (const float*)d_in[18];
    const float* out_w     = (const float*)d_in[19];
    const float* out_b     = (const float*)d_in[20];
    float* out = (float*)d_out;
    float* ws  = (float*)d_ws;

    k_kvec2  <<<656, 256, 0, stream>>>(label_emb, WK, bK, ws);
    k_weff2  <<<124, 256, 0, stream>>>(WQ, bQ, ws);
    // fused scores + unnormalized-exp softmax + attn-pool + masked maxes
    k_fused  <<<dim3(8, BB), 256, 0, stream>>>(inputs, pos_ids, subj_pos, obj_pos, ws);
    k_reduce <<<384, 256, 0, stream>>>(ws);
    // ctx_a = pooled @ WV_w.T + WV_b          (M=128,N=768,K=768)
    k_mmL<192,0><<<16 * 48, 256, 0, stream>>>(ws + OFF_POOLED, WV_w, WV_b, ws + OFF_CTXA, BB, HH);
    // ctx_b = gelu(ctx_a @ Wout_w.T + Wout_b) (M=128,N=768,K=768)
    k_mmL<192,1><<<16 * 48, 256, 0, stream>>>(ws + OFF_CTXA, Wout_w, Wout_b, ws + OFF_CTXB, BB, HH);
    k_ln     <<<BB, 256, 0, stream>>>(ln_g, ln_b, ws, out);
    // feats1 = gelu(cat @ feat_w.T + feat_b)  (M=128,N=768,K=2304)
    k_mmL<576,1><<<16 * 48, 256, 0, stream>>>(ws + OFF_CAT, feat_w, feat_b, ws + OFF_F1, BB, HH);
    // feats2 + logits fused, row-per-block
    k_tail   <<<BB, 256, 0, stream>>>(ws + OFF_F1, out_w, out_b, label_emb, out);
}

// Round 4
// 450.231 us; speedup vs baseline: 1.0425x; 1.0425x over previous
//
#include <hip/hip_runtime.h>
#include <math.h>

// Problem constants
#define BB 128
#define SS 512
#define HH 768
#define PPOS 512       // P
#define NEGC (-1.0e9f)
#define NINF (-1.0e12f)

// Workspace layout (float offsets). Regions time-multiplexed:
// phase 1 (kvec/weff/fused pool): KVEC/WEFF/C + PP/PS/PO/PZ partials
// phase 2 (reduce onward): CAT overlays dead KVEC..WEFF, CTXA..F2 overlay PP.
#define OFF_KVEC   0          // 2624  (41*64)
#define OFF_WEFF   2624       // 768
#define OFF_C      3392       // 1
#define OFF_CAT    0          // 294912 (B*2304) [subj|obj|ctx], written by k_reduce/k_ln
#define OFF_POOLED 294912     // 98304 (B*H)
#define OFF_PP     393216     // 786432 (B*8*H) partial exp-weighted pool
#define OFF_PS     1179648    // 786432 partial subj max
#define OFF_PO     1966080    // 786432 partial obj max
#define OFF_PZ     2752512    // 1024 (B*8) partial softmax denominators (end ~11MB)
#define OFF_CTXA   393216     // 98304 (overlays PP after k_reduce)
#define OFF_CTXB   491520     // 98304
#define OFF_F1     589824     // 98304
#define OFF_F2     688128     // 38400 (B*300)

__device__ __forceinline__ float gelu_f(float x) {
    return 0.5f * x * (1.0f + erff(x * 0.70710678118654752f));
}
__device__ __forceinline__ float dot4(float4 a, float4 b) {
    return a.x*b.x + a.y*b.y + a.z*b.z + a.w*b.w;
}

// ---------------------------------------------------------------------------
// Wave-tile GEMM (round-1 proven): C[M,N] = act(A[M,K] @ W[N,K]^T + bias)
// Each wave computes a 2m x 16n tile. lane = (n_sub<<2) | k_sub.
// Used for the small-W tail GEMMs (feats2, logits) where W is L2-resident.
// ---------------------------------------------------------------------------
template<int K4, int ACT, int MT>
__global__ __launch_bounds__(256) void k_mm(const float* __restrict__ A,
        const float* __restrict__ W, const float* __restrict__ bias,
        float* __restrict__ C, int M, int N) {
    int lane = threadIdx.x & 63;
    int wave = (blockIdx.x * 256 + threadIdx.x) >> 6;
    int ntn = (N + 15) >> 4;
    int m0 = (wave / ntn) * MT;
    if (m0 >= M) return;
    int n0 = ((wave % ntn) << 4) + (lane >> 2);
    int ks = lane & 3;
    bool nvalid = (n0 < N);
    const float4* A4 = (const float4*)A;
    const float4* w_row = (const float4*)W + (size_t)(nvalid ? n0 : 0) * K4;
    const float4* ar = A4 + (size_t)m0 * K4;
    float acc[MT];
    #pragma unroll
    for (int r = 0; r < MT; ++r) acc[r] = 0.f;
    #pragma unroll 4
    for (int j = ks; j < K4; j += 4) {
        float4 wv = w_row[j];
        #pragma unroll
        for (int r = 0; r < MT; ++r) acc[r] += dot4(ar[(size_t)r * K4 + j], wv);
    }
    #pragma unroll
    for (int r = 0; r < MT; ++r) {
        acc[r] += __shfl_xor(acc[r], 1, 64);
        acc[r] += __shfl_xor(acc[r], 2, 64);
    }
    if (ks == 0 && nvalid) {
        float b = bias ? bias[n0] : 0.f;
        #pragma unroll
        for (int r = 0; r < MT; ++r) {
            float v = acc[r] + b;
            if (ACT == 1) v = gelu_f(v);
            C[(size_t)(m0 + r) * N + n0] = v;
        }
    }
}

// ---------------------------------------------------------------------------
// XCD-locality wave-tile GEMM for N=768, M=128. Per-wave work IDENTICAL to
// k_mm MT=2 (no barriers, no LDS): only the block->(m,n) mapping changes.
// 768 blocks; bid&7 = XCD (round-robin dispatch). Each XCD owns a contiguous
// 6-n-tile (96-col) slice of W, m swept within the XCD, so the XCD's W
// working set is 96*K*4B (884 KB for K=2304) + 1.2 MB A panel -> fully
// L2-resident; W re-reads never fall to L3 (which was thrashing: feat_w
// 6.75 MB > 4 MB per-XCD L2 when n-tiles stripe across XCDs).
// Waves in a block share one n-tile (m-major) -> temporal W reuse in L1/L2.
// ---------------------------------------------------------------------------
template<int K4, int ACT>
__global__ __launch_bounds__(256) void k_mmX(const float* __restrict__ A,
        const float* __restrict__ W, const float* __restrict__ bias,
        float* __restrict__ C) {
    int lane = threadIdx.x & 63, wave = threadIdx.x >> 6;
    int x = blockIdx.x & 7;          // XCD
    int k = blockIdx.x >> 3;         // 0..95 within XCD
    int nb = x * 6 + (k % 6);        // n-tile 0..47 (16 cols each)
    int mb = k / 6;                  // 0..15 (8 m-rows each)
    int m0 = mb * 8 + wave * 2;
    int n_sub = lane >> 2, ks = lane & 3;
    int n0 = (nb << 4) + n_sub;
    const float4* w_row = (const float4*)W + (size_t)n0 * K4;
    const float4* ar = (const float4*)A + (size_t)m0 * K4;
    float acc0 = 0.f, acc1 = 0.f;
    #pragma unroll 4
    for (int j = ks; j < K4; j += 4) {
        float4 wv = w_row[j];
        acc0 += dot4(ar[j], wv);
        acc1 += dot4(ar[K4 + j], wv);
    }
    acc0 += __shfl_xor(acc0, 1, 64); acc0 += __shfl_xor(acc0, 2, 64);
    acc1 += __shfl_xor(acc1, 1, 64); acc1 += __shfl_xor(acc1, 2, 64);
    if (ks == 0) {
        float b = bias ? bias[n0] : 0.f;
        float v0 = acc0 + b, v1 = acc1 + b;
        if (ACT == 1) { v0 = gelu_f(v0); v1 = gelu_f(v1); }
        C[(size_t)m0 * HH + n0] = v0;
        C[(size_t)(m0 + 1) * HH + n0] = v1;
    }
}

// K1a: kvec[l,k] = sum_d label_emb[l+1,d]*WK[l,k,d] + bK[l,k].  One wave/output.
// Blocks 0..3 additionally zero-init WEFF (768) and C for k_weff2's atomics.
__global__ __launch_bounds__(256) void k_kvec2(const float* __restrict__ label_emb,
        const float* __restrict__ WK, const float* __restrict__ bK,
        float* __restrict__ ws) {
    if (blockIdx.x < 3) ws[OFF_WEFF + blockIdx.x * 256 + threadIdx.x] = 0.f;
    if (blockIdx.x == 3 && threadIdx.x == 0) ws[OFF_C] = 0.f;
    int lane = threadIdx.x & 63;
    int idx = (blockIdx.x * 256 + threadIdx.x) >> 6;   // 0..2623
    int l = idx >> 6;
    const float4* lab4 = (const float4*)(label_emb + (size_t)(l + 1) * 300);
    const float4* wk4  = (const float4*)(WK + (size_t)idx * 300);
    float acc = dot4(lab4[lane], wk4[lane]);           // 75 float4s per row
    if (lane < 11) acc += dot4(lab4[64 + lane], wk4[64 + lane]);
    #pragma unroll
    for (int off = 32; off > 0; off >>= 1) acc += __shfl_xor(acc, off, 64);
    if (lane == 0) ws[OFF_KVEC + idx] = acc + bK[idx];
}

// K1b: w_eff[h] += sum over j-chunk kvec[j]*WQ[j,h] (atomics), + c = kvec.bQ
__global__ __launch_bounds__(256) void k_weff2(const float* __restrict__ WQ,
        const float* __restrict__ bQ, float* __restrict__ ws) {
    int lane = threadIdx.x & 63;
    int w = (blockIdx.x * 256 + threadIdx.x) >> 6;
    if (w < 492) {
        int jc = w / 12, hg = w % 12;
        int h = hg * 64 + lane;
        const float* wq = WQ + (size_t)(jc * 64) * HH + h;
        const float* kv = ws + OFF_KVEC + jc * 64;
        float acc = 0.f;
        #pragma unroll 8
        for (int j = 0; j < 64; ++j) acc += kv[j] * wq[(size_t)j * HH];
        atomicAdd(&ws[OFF_WEFF + h], acc);
    } else if (w == 492) {
        float acc = 0.f;
        for (int j = lane; j < 2624; j += 64) acc += ws[OFF_KVEC + j] * bQ[j];
        #pragma unroll
        for (int off = 32; off > 0; off >>= 1) acc += __shfl_xor(acc, off, 64);
        if (lane == 0) atomicAdd(&ws[OFF_C], acc);
    }
}

// K2+K4 fused: single pass over inputs. Per row: score = (x.w_eff + c)/8,
// e = masked ? 0 : exp(score) (scores are O(0.4) by construction -> safe
// without max-subtraction; masked rows underflow to exactly 0 in the
// reference too). Accumulate sum(e*x), sum(e), and subj/obj masked maxes.
__global__ __launch_bounds__(256) void k_fused(const float* __restrict__ inputs,
        const int* __restrict__ pos_ids, const int* __restrict__ subj_pos,
        const int* __restrict__ obj_pos, float* __restrict__ ws) {
    __shared__ float l_pe[4][768];
    __shared__ float l_sm[4][768];
    __shared__ float l_om[4][768];
    __shared__ float l_z[4];
    __shared__ int l_mask[64];
    int chunk = blockIdx.x, b = blockIdx.y;
    int t = threadIdx.x, wave = t >> 6, lane = t & 63;
    int row0 = b * SS + chunk * 64;           // first global row of this block
    if (t < 64) {
        int g = row0 + t;
        int sp = subj_pos[g], op = obj_pos[g], pi = pos_ids[g];
        int m = ((sp == PPOS) | (op == PPOS) | (pi == 0)) ? 1 : 0;
        if (sp == PPOS) m |= 2;
        if (op == PPOS) m |= 4;
        l_mask[t] = m;
    }
    const float4* w4 = (const float4*)(ws + OFF_WEFF);
    float c = ws[OFF_C];
    float4 w0 = w4[lane], w1 = w4[64 + lane], w2 = w4[128 + lane];
    __syncthreads();
    const float4* in4 = (const float4*)inputs;
    float4 pe0 = make_float4(0.f, 0.f, 0.f, 0.f);
    float4 pe1 = pe0, pe2 = pe0;
    float4 sm0 = make_float4(NINF, NINF, NINF, NINF);
    float4 sm1 = sm0, sm2 = sm0, om0 = sm0, om1 = sm0, om2 = sm0;
    float z = 0.f;
    int rbase = wave * 16;                    // rows within chunk for this wave
    #pragma unroll 4
    for (int r = 0; r < 16; ++r) {
        int s = rbase + r;
        const float4* x4 = in4 + (size_t)(row0 + s) * 192;
        float4 x0 = x4[lane], x1 = x4[64 + lane], x2 = x4[128 + lane];
        float acc = dot4(x0, w0) + dot4(x1, w1) + dot4(x2, w2);
        #pragma unroll
        for (int off = 32; off > 0; off >>= 1) acc += __shfl_xor(acc, off, 64);
        int mk = l_mask[s];
        float e = (mk & 1) ? 0.f : __expf((acc + c) * 0.125f);
        z += e;
        pe0.x += e * x0.x; pe0.y += e * x0.y; pe0.z += e * x0.z; pe0.w += e * x0.w;
        pe1.x += e * x1.x; pe1.y += e * x1.y; pe1.z += e * x1.z; pe1.w += e * x1.w;
        pe2.x += e * x2.x; pe2.y += e * x2.y; pe2.z += e * x2.z; pe2.w += e * x2.w;
        if (mk & 2) {
            sm0.x = fmaxf(sm0.x, x0.x); sm0.y = fmaxf(sm0.y, x0.y);
            sm0.z = fmaxf(sm0.z, x0.z); sm0.w = fmaxf(sm0.w, x0.w);
            sm1.x = fmaxf(sm1.x, x1.x); sm1.y = fmaxf(sm1.y, x1.y);
            sm1.z = fmaxf(sm1.z, x1.z); sm1.w = fmaxf(sm1.w, x1.w);
            sm2.x = fmaxf(sm2.x, x2.x); sm2.y = fmaxf(sm2.y, x2.y);
            sm2.z = fmaxf(sm2.z, x2.z); sm2.w = fmaxf(sm2.w, x2.w);
        }
        if (mk & 4) {
            om0.x = fmaxf(om0.x, x0.x); om0.y = fmaxf(om0.y, x0.y);
            om0.z = fmaxf(om0.z, x0.z); om0.w = fmaxf(om0.w, x0.w);
            om1.x = fmaxf(om1.x, x1.x); om1.y = fmaxf(om1.y, x1.y);
            om1.z = fmaxf(om1.z, x1.z); om1.w = fmaxf(om1.w, x1.w);
            om2.x = fmaxf(om2.x, x2.x); om2.y = fmaxf(om2.y, x2.y);
            om2.z = fmaxf(om2.z, x2.z); om2.w = fmaxf(om2.w, x2.w);
        }
    }
    // wave partials -> LDS (h layout: [lane*4..+3], [256+..], [512+..])
    ((float4*)l_pe[wave])[lane] = pe0;
    ((float4*)l_pe[wave])[64 + lane] = pe1;
    ((float4*)l_pe[wave])[128 + lane] = pe2;
    ((float4*)l_sm[wave])[lane] = sm0;
    ((float4*)l_sm[wave])[64 + lane] = sm1;
    ((float4*)l_sm[wave])[128 + lane] = sm2;
    ((float4*)l_om[wave])[lane] = om0;
    ((float4*)l_om[wave])[64 + lane] = om1;
    ((float4*)l_om[wave])[128 + lane] = om2;
    if (lane == 0) l_z[wave] = z;
    __syncthreads();
    if (t < 192) {
        float4 p = make_float4(0.f, 0.f, 0.f, 0.f);
        float4 s = make_float4(NINF, NINF, NINF, NINF);
        float4 o = s;
        #pragma unroll
        for (int w = 0; w < 4; ++w) {
            float4 vp = ((float4*)l_pe[w])[t];
            float4 vs = ((float4*)l_sm[w])[t];
            float4 vo = ((float4*)l_om[w])[t];
            p.x += vp.x; p.y += vp.y; p.z += vp.z; p.w += vp.w;
            s.x = fmaxf(s.x, vs.x); s.y = fmaxf(s.y, vs.y);
            s.z = fmaxf(s.z, vs.z); s.w = fmaxf(s.w, vs.w);
            o.x = fmaxf(o.x, vo.x); o.y = fmaxf(o.y, vo.y);
            o.z = fmaxf(o.z, vo.z); o.w = fmaxf(o.w, vo.w);
        }
        size_t oo = (size_t)(b * 8 + chunk) * 192 + t;
        ((float4*)(ws + OFF_PP))[oo] = p;
        ((float4*)(ws + OFF_PS))[oo] = s;
        ((float4*)(ws + OFF_PO))[oo] = o;
    }
    if (t == 0) ws[OFF_PZ + b * 8 + chunk] = l_z[0] + l_z[1] + l_z[2] + l_z[3];
}

// K5: reduce 8 chunk partials -> pooled (/Z), and subj/obj maxes into CAT
__global__ void k_reduce(float* __restrict__ ws) {
    int i = blockIdx.x * 256 + threadIdx.x;   // 0..98303
    int b = i / HH, h = i - b * HH;
    float p = 0.f, sm = NINF, om = NINF, zt = 0.f;
    #pragma unroll
    for (int j = 0; j < 8; ++j) {
        int o = (b * 8 + j) * HH + h;
        p += ws[OFF_PP + o];
        sm = fmaxf(sm, ws[OFF_PS + o]);
        om = fmaxf(om, ws[OFF_PO + o]);
        zt += ws[OFF_PZ + b * 8 + j];
    }
    ws[OFF_POOLED + i] = p / zt;
    ws[OFF_CAT + (size_t)b * 2304 + h] = sm;
    ws[OFF_CAT + (size_t)b * 2304 + 768 + h] = om;
}

// K8: layernorm -> ctx output (d_out offset 5376) AND cat[:, 1536:2304]
__global__ void k_ln(const float* __restrict__ ln_g, const float* __restrict__ ln_b,
                     float* __restrict__ ws, float* __restrict__ out) {
    __shared__ float red[256];
    __shared__ float red2[256];
    int b = blockIdx.x, t = threadIdx.x;
    const float* x = ws + OFF_CTXB + (size_t)b * HH;
    float a0 = x[t], a1 = x[t + 256], a2 = x[t + 512];
    red[t]  = a0 + a1 + a2;
    red2[t] = a0 * a0 + a1 * a1 + a2 * a2;
    __syncthreads();
    for (int s2 = 128; s2 > 0; s2 >>= 1) {
        if (t < s2) { red[t] += red[t + s2]; red2[t] += red2[t + s2]; }
        __syncthreads();
    }
    float mu  = red[0] * (1.0f / 768.0f);
    float var = red2[0] * (1.0f / 768.0f) - mu * mu;
    float inv = rsqrtf(var + 1e-5f);
    float* o = out + 5376 + (size_t)b * HH;
    float* cc = ws + OFF_CAT + (size_t)b * 2304 + 1536;
    float r0 = (a0 - mu) * inv * ln_g[t]       + ln_b[t];
    float r1 = (a1 - mu) * inv * ln_g[t + 256] + ln_b[t + 256];
    float r2 = (a2 - mu) * inv * ln_g[t + 512] + ln_b[t + 512];
    o[t] = r0; o[t + 256] = r1; o[t + 512] = r2;
    cc[t] = r0; cc[t + 256] = r1; cc[t + 512] = r2;
}

extern "C" void kernel_launch(void* const* d_in, const int* in_sizes, int n_in,
                              void* d_out, int out_size, void* d_ws, size_t ws_size,
                              hipStream_t stream) {
    const float* inputs    = (const float*)d_in[0];
    const int*   pos_ids   = (const int*)d_in[1];
    const int*   subj_pos  = (const int*)d_in[3];
    const int*   obj_pos   = (const int*)d_in[4];
    const float* WQ        = (const float*)d_in[6];
    const float* bQ        = (const float*)d_in[7];
    const float* WK        = (const float*)d_in[8];
    const float* bK        = (const float*)d_in[9];
    const float* WV_w      = (const float*)d_in[10];
    const float* WV_b      = (const float*)d_in[11];
    const float* Wout_w    = (const float*)d_in[12];
    const float* Wout_b    = (const float*)d_in[13];
    const float* ln_g      = (const float*)d_in[14];
    const float* ln_b      = (const float*)d_in[15];
    const float* label_emb = (const float*)d_in[16];
    const float* feat_w    = (const float*)d_in[17];
    const float* feat_b    = (const float*)d_in[18];
    const float* out_w     = (const float*)d_in[19];
    const float* out_b     = (const float*)d_in[20];
    float* out = (float*)d_out;
    float* ws  = (float*)d_ws;

    k_kvec2  <<<656, 256, 0, stream>>>(label_emb, WK, bK, ws);
    k_weff2  <<<124, 256, 0, stream>>>(WQ, bQ, ws);
    // fused scores + unnormalized-exp softmax + attn-pool + masked maxes
    k_fused  <<<dim3(8, BB), 256, 0, stream>>>(inputs, pos_ids, subj_pos, obj_pos, ws);
    k_reduce <<<384, 256, 0, stream>>>(ws);
    // ctx_a = pooled @ WV_w.T + WV_b          (M=128,N=768,K=768)
    k_mmX<192,0><<<768, 256, 0, stream>>>(ws + OFF_POOLED, WV_w, WV_b, ws + OFF_CTXA);
    // ctx_b = gelu(ctx_a @ Wout_w.T + Wout_b) (M=128,N=768,K=768)
    k_mmX<192,1><<<768, 256, 0, stream>>>(ws + OFF_CTXA, Wout_w, Wout_b, ws + OFF_CTXB);
    k_ln     <<<BB, 256, 0, stream>>>(ln_g, ln_b, ws, out);
    // feats1 = gelu(cat @ feat_w.T + feat_b)  (M=128,N=768,K=2304)
    k_mmX<576,1><<<768, 256, 0, stream>>>(ws + OFF_CAT, feat_w, feat_b, ws + OFF_F1);
    // feats2 = gelu(f1 @ out_w.T + out_b)     (M=128,N=300,K=768)
    k_mm<192,1,2><<<304, 256, 0, stream>>>(ws + OFF_F1, out_w, out_b, ws + OFF_F2, BB, 300);
    // logits = f2 @ label_emb.T               (M=128,N=42,K=300)
    k_mm<75,0,2><<<48, 256, 0, stream>>>(ws + OFF_F2, label_emb, nullptr, out, BB, 42);
}

// Round 5
// 449.905 us; speedup vs baseline: 1.0433x; 1.0007x over previous
//
#include <hip/hip_runtime.h>
#include <math.h>

// Problem constants
#define BB 128
#define SS 512
#define HH 768
#define PPOS 512       // P
#define NINF (-1.0e12f)

// Workspace layout (float offsets). KVEC/WEFF/C/Z live through phase 1.
// POOLED/Z/CAT are atomic accumulators initialized by k_kvec2 each iteration.
// CAT sits in its own region (NOT overlaying KVEC) because k_fused's atomics
// run while WEFF/C are still being read.
#define OFF_KVEC   0        // 2624  (41*64)
#define OFF_WEFF   2624     // 768
#define OFF_C      3392     // 1
#define OFF_Z      3456     // 128   (B) softmax denominators, atomicAdd
#define OFF_POOLED 294912   // 98304 (B*H) unnormalized pool, atomicAdd
#define OFF_CAT    393216   // 294912 (B*2304) [subj-keys|obj-keys|ctx]
#define OFF_CTXA   688128   // 98304
#define OFF_CTXB   786432   // 98304
#define OFF_F1     884736   // 98304
#define OFF_F2     983040   // 38400 (B*300); end 1021440 floats ~4.1 MB

#define N_INIT 295040       // 98304 pooled + 128 Z + 196608 CAT keys
#define INIT_THREADS 167936 // 656 blocks * 256

__device__ __forceinline__ float gelu_f(float x) {
    return 0.5f * x * (1.0f + erff(x * 0.70710678118654752f));
}
__device__ __forceinline__ float dot4(float4 a, float4 b) {
    return a.x*b.x + a.y*b.y + a.z*b.z + a.w*b.w;
}
// order-preserving f32 <-> u32 key (for atomicMax on floats of mixed sign)
__device__ __forceinline__ unsigned fkey(float f) {
    unsigned u = __float_as_uint(f);
    return (u & 0x80000000u) ? ~u : (u | 0x80000000u);
}
__device__ __forceinline__ float fkey_dec(unsigned k) {
    return __uint_as_float((k & 0x80000000u) ? (k & 0x7fffffffu) : ~k);
}

// ---------------------------------------------------------------------------
// Wave-tile GEMM (round-1 proven): C[M,N] = act(A[M,K] @ W[N,K]^T + bias)
// Used for the small-W tail GEMMs (feats2, logits) where W is L2-resident.
// ---------------------------------------------------------------------------
template<int K4, int ACT, int MT>
__global__ __launch_bounds__(256) void k_mm(const float* __restrict__ A,
        const float* __restrict__ W, const float* __restrict__ bias,
        float* __restrict__ C, int M, int N) {
    int lane = threadIdx.x & 63;
    int wave = (blockIdx.x * 256 + threadIdx.x) >> 6;
    int ntn = (N + 15) >> 4;
    int m0 = (wave / ntn) * MT;
    if (m0 >= M) return;
    int n0 = ((wave % ntn) << 4) + (lane >> 2);
    int ks = lane & 3;
    bool nvalid = (n0 < N);
    const float4* A4 = (const float4*)A;
    const float4* w_row = (const float4*)W + (size_t)(nvalid ? n0 : 0) * K4;
    const float4* ar = A4 + (size_t)m0 * K4;
    float acc[MT];
    #pragma unroll
    for (int r = 0; r < MT; ++r) acc[r] = 0.f;
    #pragma unroll 4
    for (int j = ks; j < K4; j += 4) {
        float4 wv = w_row[j];
        #pragma unroll
        for (int r = 0; r < MT; ++r) acc[r] += dot4(ar[(size_t)r * K4 + j], wv);
    }
    #pragma unroll
    for (int r = 0; r < MT; ++r) {
        acc[r] += __shfl_xor(acc[r], 1, 64);
        acc[r] += __shfl_xor(acc[r], 2, 64);
    }
    if (ks == 0 && nvalid) {
        float b = bias ? bias[n0] : 0.f;
        #pragma unroll
        for (int r = 0; r < MT; ++r) {
            float v = acc[r] + b;
            if (ACT == 1) v = gelu_f(v);
            C[(size_t)(m0 + r) * N + n0] = v;
        }
    }
}

// ---------------------------------------------------------------------------
// XCD-locality wave-tile GEMM for N=768, M=128 (R4 proven, +optional 1/Z
// epilogue scale for the pooled->ctx_a GEMM: (pool/Z)@W + b == (pool@W)/Z + b).
// ---------------------------------------------------------------------------
template<int K4, int ACT>
__global__ __launch_bounds__(256) void k_mmX(const float* __restrict__ A,
        const float* __restrict__ W, const float* __restrict__ bias,
        float* __restrict__ C, const float* __restrict__ Zv) {
    int lane = threadIdx.x & 63, wave = threadIdx.x >> 6;
    int x = blockIdx.x & 7;          // XCD
    int k = blockIdx.x >> 3;         // 0..95 within XCD
    int nb = x * 6 + (k % 6);        // n-tile 0..47 (16 cols each)
    int mb = k / 6;                  // 0..15 (8 m-rows each)
    int m0 = mb * 8 + wave * 2;
    int n_sub = lane >> 2, ks = lane & 3;
    int n0 = (nb << 4) + n_sub;
    const float4* w_row = (const float4*)W + (size_t)n0 * K4;
    const float4* ar = (const float4*)A + (size_t)m0 * K4;
    float acc0 = 0.f, acc1 = 0.f;
    #pragma unroll 4
    for (int j = ks; j < K4; j += 4) {
        float4 wv = w_row[j];
        acc0 += dot4(ar[j], wv);
        acc1 += dot4(ar[K4 + j], wv);
    }
    acc0 += __shfl_xor(acc0, 1, 64); acc0 += __shfl_xor(acc0, 2, 64);
    acc1 += __shfl_xor(acc1, 1, 64); acc1 += __shfl_xor(acc1, 2, 64);
    if (ks == 0) {
        float b = bias ? bias[n0] : 0.f;
        float v0, v1;
        if (Zv) {
            v0 = acc0 * (1.f / Zv[m0]) + b;
            v1 = acc1 * (1.f / Zv[m0 + 1]) + b;
        } else {
            v0 = acc0 + b;
            v1 = acc1 + b;
        }
        if (ACT == 1) { v0 = gelu_f(v0); v1 = gelu_f(v1); }
        C[(size_t)m0 * HH + n0] = v0;
        C[(size_t)(m0 + 1) * HH + n0] = v1;
    }
}

// K1a: kvec[l,k] = sum_d label_emb[l+1,d]*WK[l,k,d] + bK[l,k].  One wave/output.
// Blocks 0..3 zero WEFF/C for k_weff2's atomics. ALL blocks additionally init
// the atomic accumulators consumed later: POOLED=0, Z=0, CAT subj/obj = key(NINF).
__global__ __launch_bounds__(256) void k_kvec2(const float* __restrict__ label_emb,
        const float* __restrict__ WK, const float* __restrict__ bK,
        float* __restrict__ ws) {
    if (blockIdx.x < 3) ws[OFF_WEFF + blockIdx.x * 256 + threadIdx.x] = 0.f;
    if (blockIdx.x == 3 && threadIdx.x == 0) ws[OFF_C] = 0.f;
    // strided init of POOLED / Z / CAT-keys (2 slots per thread)
    unsigned keyn = fkey(NINF);
    int tid = blockIdx.x * 256 + threadIdx.x;
    for (int idx = tid; idx < N_INIT; idx += INIT_THREADS) {
        if (idx < 98304) ws[OFF_POOLED + idx] = 0.f;
        else if (idx < 98432) ws[OFF_Z + (idx - 98304)] = 0.f;
        else {
            int cidx = idx - 98432;            // 0..196607
            int b = cidx / 1536, off = cidx - b * 1536;
            ((unsigned*)ws)[OFF_CAT + b * 2304 + off] = keyn;
        }
    }
    int lane = threadIdx.x & 63;
    int idx = (blockIdx.x * 256 + threadIdx.x) >> 6;   // 0..2623
    int l = idx >> 6;
    const float4* lab4 = (const float4*)(label_emb + (size_t)(l + 1) * 300);
    const float4* wk4  = (const float4*)(WK + (size_t)idx * 300);
    float acc = dot4(lab4[lane], wk4[lane]);           // 75 float4s per row
    if (lane < 11) acc += dot4(lab4[64 + lane], wk4[64 + lane]);
    #pragma unroll
    for (int off = 32; off > 0; off >>= 1) acc += __shfl_xor(acc, off, 64);
    if (lane == 0) ws[OFF_KVEC + idx] = acc + bK[idx];
}

// K1b: w_eff[h] += sum over j-chunk kvec[j]*WQ[j,h] (atomics), + c = kvec.bQ
__global__ __launch_bounds__(256) void k_weff2(const float* __restrict__ WQ,
        const float* __restrict__ bQ, float* __restrict__ ws) {
    int lane = threadIdx.x & 63;
    int w = (blockIdx.x * 256 + threadIdx.x) >> 6;
    if (w < 492) {
        int jc = w / 12, hg = w % 12;
        int h = hg * 64 + lane;
        const float* wq = WQ + (size_t)(jc * 64) * HH + h;
        const float* kv = ws + OFF_KVEC + jc * 64;
        float acc = 0.f;
        #pragma unroll 8
        for (int j = 0; j < 64; ++j) acc += kv[j] * wq[(size_t)j * HH];
        atomicAdd(&ws[OFF_WEFF + h], acc);
    } else if (w == 492) {
        float acc = 0.f;
        for (int j = lane; j < 2624; j += 64) acc += ws[OFF_KVEC + j] * bQ[j];
        #pragma unroll
        for (int off = 32; off > 0; off >>= 1) acc += __shfl_xor(acc, off, 64);
        if (lane == 0) atomicAdd(&ws[OFF_C], acc);
    }
}

// K2+K4+K5 fused: single pass over inputs. Per row: score=(x.w_eff+c)/8,
// e = masked ? 0 : exp(score) (scores O(0.4) -> safe unnormalized). Block
// partials combine in LDS, then go DIRECTLY to the final accumulators via
// device-scope atomics: pool/Z by atomicAdd, subj/obj maxes by atomicMax on
// monotone u32 keys. This removes the k_reduce stage + 19 MB partial traffic.
__global__ __launch_bounds__(256) void k_fused(const float* __restrict__ inputs,
        const int* __restrict__ pos_ids, const int* __restrict__ subj_pos,
        const int* __restrict__ obj_pos, float* __restrict__ ws) {
    __shared__ float l_pe[4][768];
    __shared__ float l_sm[4][768];
    __shared__ float l_om[4][768];
    __shared__ float l_z[4];
    __shared__ int l_mask[64];
    __shared__ int sflag, oflag;
    int chunk = blockIdx.x, b = blockIdx.y;
    int t = threadIdx.x, wave = t >> 6, lane = t & 63;
    int row0 = b * SS + chunk * 64;           // first global row of this block
    if (t < 64) {                             // == all of wave 0
        int g = row0 + t;
        int sp = subj_pos[g], op = obj_pos[g], pi = pos_ids[g];
        int m = ((sp == PPOS) | (op == PPOS) | (pi == 0)) ? 1 : 0;
        if (sp == PPOS) m |= 2;
        if (op == PPOS) m |= 4;
        l_mask[t] = m;
        unsigned long long bs = __ballot((m & 2) != 0);
        unsigned long long bo = __ballot((m & 4) != 0);
        if (t == 0) { sflag = bs ? 1 : 0; oflag = bo ? 1 : 0; }
    }
    const float4* w4 = (const float4*)(ws + OFF_WEFF);
    float c = ws[OFF_C];
    float4 w0 = w4[lane], w1 = w4[64 + lane], w2 = w4[128 + lane];
    __syncthreads();
    const float4* in4 = (const float4*)inputs;
    float4 pe0 = make_float4(0.f, 0.f, 0.f, 0.f);
    float4 pe1 = pe0, pe2 = pe0;
    float4 sm0 = make_float4(NINF, NINF, NINF, NINF);
    float4 sm1 = sm0, sm2 = sm0, om0 = sm0, om1 = sm0, om2 = sm0;
    float z = 0.f;
    int rbase = wave * 16;                    // rows within chunk for this wave
    #pragma unroll 4
    for (int r = 0; r < 16; ++r) {
        int s = rbase + r;
        const float4* x4 = in4 + (size_t)(row0 + s) * 192;
        float4 x0 = x4[lane], x1 = x4[64 + lane], x2 = x4[128 + lane];
        float acc = dot4(x0, w0) + dot4(x1, w1) + dot4(x2, w2);
        #pragma unroll
        for (int off = 32; off > 0; off >>= 1) acc += __shfl_xor(acc, off, 64);
        int mk = l_mask[s];
        float e = (mk & 1) ? 0.f : __expf((acc + c) * 0.125f);
        z += e;
        pe0.x += e * x0.x; pe0.y += e * x0.y; pe0.z += e * x0.z; pe0.w += e * x0.w;
        pe1.x += e * x1.x; pe1.y += e * x1.y; pe1.z += e * x1.z; pe1.w += e * x1.w;
        pe2.x += e * x2.x; pe2.y += e * x2.y; pe2.z += e * x2.z; pe2.w += e * x2.w;
        if (mk & 2) {
            sm0.x = fmaxf(sm0.x, x0.x); sm0.y = fmaxf(sm0.y, x0.y);
            sm0.z = fmaxf(sm0.z, x0.z); sm0.w = fmaxf(sm0.w, x0.w);
            sm1.x = fmaxf(sm1.x, x1.x); sm1.y = fmaxf(sm1.y, x1.y);
            sm1.z = fmaxf(sm1.z, x1.z); sm1.w = fmaxf(sm1.w, x1.w);
            sm2.x = fmaxf(sm2.x, x2.x); sm2.y = fmaxf(sm2.y, x2.y);
            sm2.z = fmaxf(sm2.z, x2.z); sm2.w = fmaxf(sm2.w, x2.w);
        }
        if (mk & 4) {
            om0.x = fmaxf(om0.x, x0.x); om0.y = fmaxf(om0.y, x0.y);
            om0.z = fmaxf(om0.z, x0.z); om0.w = fmaxf(om0.w, x0.w);
            om1.x = fmaxf(om1.x, x1.x); om1.y = fmaxf(om1.y, x1.y);
            om1.z = fmaxf(om1.z, x1.z); om1.w = fmaxf(om1.w, x1.w);
            om2.x = fmaxf(om2.x, x2.x); om2.y = fmaxf(om2.y, x2.y);
            om2.z = fmaxf(om2.z, x2.z); om2.w = fmaxf(om2.w, x2.w);
        }
    }
    // wave partials -> LDS
    ((float4*)l_pe[wave])[lane] = pe0;
    ((float4*)l_pe[wave])[64 + lane] = pe1;
    ((float4*)l_pe[wave])[128 + lane] = pe2;
    ((float4*)l_sm[wave])[lane] = sm0;
    ((float4*)l_sm[wave])[64 + lane] = sm1;
    ((float4*)l_sm[wave])[128 + lane] = sm2;
    ((float4*)l_om[wave])[lane] = om0;
    ((float4*)l_om[wave])[64 + lane] = om1;
    ((float4*)l_om[wave])[128 + lane] = om2;
    if (lane == 0) l_z[wave] = z;
    __syncthreads();
    if (t < 192) {
        float4 p = make_float4(0.f, 0.f, 0.f, 0.f);
        float4 s = make_float4(NINF, NINF, NINF, NINF);
        float4 o = s;
        #pragma unroll
        for (int w = 0; w < 4; ++w) {
            float4 vp = ((float4*)l_pe[w])[t];
            float4 vs = ((float4*)l_sm[w])[t];
            float4 vo = ((float4*)l_om[w])[t];
            p.x += vp.x; p.y += vp.y; p.z += vp.z; p.w += vp.w;
            s.x = fmaxf(s.x, vs.x); s.y = fmaxf(s.y, vs.y);
            s.z = fmaxf(s.z, vs.z); s.w = fmaxf(s.w, vs.w);
            o.x = fmaxf(o.x, vo.x); o.y = fmaxf(o.y, vo.y);
            o.z = fmaxf(o.z, vo.z); o.w = fmaxf(o.w, vo.w);
        }
        int hb = t * 4;
        float* pooled = ws + OFF_POOLED + (size_t)b * HH + hb;
        atomicAdd(&pooled[0], p.x); atomicAdd(&pooled[1], p.y);
        atomicAdd(&pooled[2], p.z); atomicAdd(&pooled[3], p.w);
        if (sflag) {
            unsigned* sk = (unsigned*)ws + OFF_CAT + (size_t)b * 2304 + hb;
            atomicMax(&sk[0], fkey(s.x)); atomicMax(&sk[1], fkey(s.y));
            atomicMax(&sk[2], fkey(s.z)); atomicMax(&sk[3], fkey(s.w));
        }
        if (oflag) {
            unsigned* ok = (unsigned*)ws + OFF_CAT + (size_t)b * 2304 + 768 + hb;
            atomicMax(&ok[0], fkey(o.x)); atomicMax(&ok[1], fkey(o.y));
            atomicMax(&ok[2], fkey(o.z)); atomicMax(&ok[3], fkey(o.w));
        }
    }
    if (t == 0) atomicAdd(&ws[OFF_Z + b], l_z[0] + l_z[1] + l_z[2] + l_z[3]);
}

// K8: decode CAT subj/obj keys -> floats, then layernorm -> ctx output
// (d_out offset 5376) AND cat[:, 1536:2304]
__global__ void k_ln(const float* __restrict__ ln_g, const float* __restrict__ ln_b,
                     float* __restrict__ ws, float* __restrict__ out) {
    __shared__ float red[256];
    __shared__ float red2[256];
    int b = blockIdx.x, t = threadIdx.x;
    // decode this batch's 1536 subj/obj keys in place (disjoint from ln data)
    unsigned* ck = (unsigned*)ws + OFF_CAT + (size_t)b * 2304;
    #pragma unroll
    for (int i = t; i < 1536; i += 256)
        ((float*)ck)[i] = fkey_dec(ck[i]);
    const float* x = ws + OFF_CTXB + (size_t)b * HH;
    float a0 = x[t], a1 = x[t + 256], a2 = x[t + 512];
    red[t]  = a0 + a1 + a2;
    red2[t] = a0 * a0 + a1 * a1 + a2 * a2;
    __syncthreads();
    for (int s2 = 128; s2 > 0; s2 >>= 1) {
        if (t < s2) { red[t] += red[t + s2]; red2[t] += red2[t + s2]; }
        __syncthreads();
    }
    float mu  = red[0] * (1.0f / 768.0f);
    float var = red2[0] * (1.0f / 768.0f) - mu * mu;
    float inv = rsqrtf(var + 1e-5f);
    float* o = out + 5376 + (size_t)b * HH;
    float* cc = ws + OFF_CAT + (size_t)b * 2304 + 1536;
    float r0 = (a0 - mu) * inv * ln_g[t]       + ln_b[t];
    float r1 = (a1 - mu) * inv * ln_g[t + 256] + ln_b[t + 256];
    float r2 = (a2 - mu) * inv * ln_g[t + 512] + ln_b[t + 512];
    o[t] = r0; o[t + 256] = r1; o[t + 512] = r2;
    cc[t] = r0; cc[t + 256] = r1; cc[t + 512] = r2;
}

extern "C" void kernel_launch(void* const* d_in, const int* in_sizes, int n_in,
                              void* d_out, int out_size, void* d_ws, size_t ws_size,
                              hipStream_t stream) {
    const float* inputs    = (const float*)d_in[0];
    const int*   pos_ids   = (const int*)d_in[1];
    const int*   subj_pos  = (const int*)d_in[3];
    const int*   obj_pos   = (const int*)d_in[4];
    const float* WQ        = (const float*)d_in[6];
    const float* bQ        = (const float*)d_in[7];
    const float* WK        = (const float*)d_in[8];
    const float* bK        = (const float*)d_in[9];
    const float* WV_w      = (const float*)d_in[10];
    const float* WV_b      = (const float*)d_in[11];
    const float* Wout_w    = (const float*)d_in[12];
    const float* Wout_b    = (const float*)d_in[13];
    const float* ln_g      = (const float*)d_in[14];
    const float* ln_b      = (const float*)d_in[15];
    const float* label_emb = (const float*)d_in[16];
    const float* feat_w    = (const float*)d_in[17];
    const float* feat_b    = (const float*)d_in[18];
    const float* out_w     = (const float*)d_in[19];
    const float* out_b     = (const float*)d_in[20];
    float* out = (float*)d_out;
    float* ws  = (float*)d_ws;

    k_kvec2  <<<656, 256, 0, stream>>>(label_emb, WK, bK, ws);
    k_weff2  <<<124, 256, 0, stream>>>(WQ, bQ, ws);
    // fused scores + unnormalized-exp softmax + attn-pool + masked maxes,
    // accumulating straight into POOLED/Z/CAT via atomics (no k_reduce stage)
    k_fused  <<<dim3(8, BB), 256, 0, stream>>>(inputs, pos_ids, subj_pos, obj_pos, ws);
    // ctx_a = (pooled/Z) @ WV_w.T + WV_b      (M=128,N=768,K=768; /Z in epilogue)
    k_mmX<192,0><<<768, 256, 0, stream>>>(ws + OFF_POOLED, WV_w, WV_b, ws + OFF_CTXA, ws + OFF_Z);
    // ctx_b = gelu(ctx_a @ Wout_w.T + Wout_b) (M=128,N=768,K=768)
    k_mmX<192,1><<<768, 256, 0, stream>>>(ws + OFF_CTXA, Wout_w, Wout_b, ws + OFF_CTXB, nullptr);
    k_ln     <<<BB, 256, 0, stream>>>(ln_g, ln_b, ws, out);
    // feats1 = gelu(cat @ feat_w.T + feat_b)  (M=128,N=768,K=2304)
    k_mmX<576,1><<<768, 256, 0, stream>>>(ws + OFF_CAT, feat_w, feat_b, ws + OFF_F1, nullptr);
    // feats2 = gelu(f1 @ out_w.T + out_b)     (M=128,N=300,K=768)
    k_mm<192,1,2><<<304, 256, 0, stream>>>(ws + OFF_F1, out_w, out_b, ws + OFF_F2, BB, 300);
    // logits = f2 @ label_emb.T               (M=128,N=42,K=300)
    k_mm<75,0,2><<<48, 256, 0, stream>>>(ws + OFF_F2, label_emb, nullptr, out, BB, 42);
}